// Round 2
// baseline (525.254 us; speedup 1.0000x reference)
//
#include <hip/hip_runtime.h>

// reset_layer: Out = R^T · X · L^T + X per (b,h,w), where X is the 10x10 grid
// of 200x200 tiles of the 2000x2000 image. Fully fused single pass.
// x (16,2000,2000) fp32, bs=10  ->  2000 % 10 == 0, no padding.
//
// Structure: per-thread X[10][10] resident; stream over output column-chunk
// pairs (j0,j1): Ycol = X·L[j]^T (transient 10), Z[:,j] = R^T·Ycol + X[:,j],
// store immediately. Peak regs ~ X(100) + transients(~60) -- no spill, vs the
// X+Y fully-resident version that sat at the 256-VGPR cap.

#define IMG  2000
#define BSZ  10
#define TC   200                 // chunk size = 2000/10
#define CHW  (IMG * IMG)         // 4,000,000
#define ROWSTEP (TC * IMG)       // 400,000

__global__ __launch_bounds__(256, 2)
void reset_block_mix2(const float* __restrict__ x,
                      const float* __restrict__ leftm,
                      const float* __restrict__ rightm,
                      float* __restrict__ out)
{
    // Padded to 12 floats/row so each row is 3 aligned float4s (ds_read_b128).
    __shared__ __align__(16) float Ls[BSZ][12];   // Ls[jW][iW] = L[jW][iW]
    __shared__ __align__(16) float Rt[BSZ][12];   // Rt[jH][iH] = R[iH][jH]
    {
        const int t = threadIdx.x;
        if (t < 120) {
            const int r = t / 12, c = t - r * 12;
            Ls[r][c] = (c < BSZ) ? leftm[r * BSZ + c] : 0.0f;
        } else if (t < 240) {
            const int u = t - 120;
            const int r = u / 12, c = u - r * 12;
            Rt[r][c] = (c < BSZ) ? rightm[c * BSZ + r] : 0.0f;
        }
    }
    __syncthreads();

    const int idx = blockIdx.x * 256 + threadIdx.x;  // 2500 blocks -> exact cover
    const int w   = idx % TC;
    const int tm  = idx / TC;
    const int h   = tm % TC;
    const int b   = tm / TC;
    const int base = b * CHW + h * IMG + w;

    // ---- load full per-pixel 10x10 block matrix (100 coalesced loads, max MLP)
    float X[BSZ][BSZ];
    #pragma unroll
    for (int ih = 0; ih < BSZ; ++ih) {
        const int rb = base + ih * ROWSTEP;
        #pragma unroll
        for (int iw = 0; iw < BSZ; ++iw)
            X[ih][iw] = x[rb + iw * TC];
    }

    // ---- stream over output column-chunk pairs ----
    #pragma unroll 1
    for (int jp = 0; jp < BSZ / 2; ++jp) {
        const int j0 = 2 * jp, j1 = 2 * jp + 1;

        // Opaque zero: makes Rt reads loop-variant so LICM can't hoist
        // 120 floats of coefficients out of the loop (VGPR spill hazard).
        int zoff = 0;
        asm volatile("" : "+v"(zoff));

        const float4* lrow0 = (const float4*)&Ls[j0][0];
        const float4* lrow1 = (const float4*)&Ls[j1][0];
        const float4 l0a = lrow0[0], l0b = lrow0[1], l0c = lrow0[2];
        const float4 l1a = lrow1[0], l1b = lrow1[1], l1c = lrow1[2];

        // Ycol[ih] = sum_iw L[j][iw] * X[ih][iw]
        float y0[BSZ], y1[BSZ];
        #pragma unroll
        for (int ih = 0; ih < BSZ; ++ih) {
            y0[ih] = l0a.x*X[ih][0] + l0a.y*X[ih][1] + l0a.z*X[ih][2] + l0a.w*X[ih][3]
                   + l0b.x*X[ih][4] + l0b.y*X[ih][5] + l0b.z*X[ih][6] + l0b.w*X[ih][7]
                   + l0c.x*X[ih][8] + l0c.y*X[ih][9];
            y1[ih] = l1a.x*X[ih][0] + l1a.y*X[ih][1] + l1a.z*X[ih][2] + l1a.w*X[ih][3]
                   + l1b.x*X[ih][4] + l1b.y*X[ih][5] + l1b.z*X[ih][6] + l1b.w*X[ih][7]
                   + l1c.x*X[ih][8] + l1c.y*X[ih][9];
        }

        // Z[jh] = sum_ih Rt[jh][ih] * Ycol[ih] + X[jh][j], store immediately.
        const float4* rt = (const float4*)((const float*)&Rt[0][0] + zoff);
        #pragma unroll
        for (int jh = 0; jh < BSZ; ++jh) {
            const float4 ra = rt[jh * 3 + 0];
            const float4 rb = rt[jh * 3 + 1];
            const float4 rc = rt[jh * 3 + 2];
            const float z0 = ra.x*y0[0] + ra.y*y0[1] + ra.z*y0[2] + ra.w*y0[3]
                           + rb.x*y0[4] + rb.y*y0[5] + rb.z*y0[6] + rb.w*y0[7]
                           + rc.x*y0[8] + rc.y*y0[9] + X[jh][j0];
            const float z1 = ra.x*y1[0] + ra.y*y1[1] + ra.z*y1[2] + ra.w*y1[3]
                           + rb.x*y1[4] + rb.y*y1[5] + rb.z*y1[6] + rb.w*y1[7]
                           + rc.x*y1[8] + rc.y*y1[9] + X[jh][j1];
            const int ob = base + jh * ROWSTEP;
            out[ob + j0 * TC] = z0;
            out[ob + j1 * TC] = z1;
        }
    }
}

extern "C" void kernel_launch(void* const* d_in, const int* in_sizes, int n_in,
                              void* d_out, int out_size, void* d_ws, size_t ws_size,
                              hipStream_t stream) {
    const float* x = (const float*)d_in[0];
    const float* L = (const float*)d_in[1];
    const float* R = (const float*)d_in[2];
    float* out = (float*)d_out;
    // 16 * 200 * 200 = 640,000 threads -> 2500 blocks of 256, exact cover.
    reset_block_mix2<<<2500, 256, 0, stream>>>(x, L, R, out);
}

// Round 3
// 421.035 us; speedup vs baseline: 1.2475x; 1.2475x over previous
//
#include <hip/hip_runtime.h>

// reset_layer: Out = R^T · X_grid · L^T + X per pixel-group, x (16,2000,2000)
// fp32, bs=10 (no padding). Block = one (b,h) "row line": the 10 image rows
// {h + ih*200}, each a contiguous 8 KB span -> every global load/store
// instruction covers ~800-1024 contiguous bytes (vs the 256B@stride-800B
// scatter of the per-thread-pixel layout that plateaued at 3.5 TB/s).
//
// Thread (ih, wo4) holds its 40-float X row-slice in registers the whole
// time; W-mix (Y = X·L^T) goes through an 80 KB LDS buffer; after one
// barrier the H-mix accumulates R^T·Y *into the X registers* (output row
// jh == ih, so the identity term is already resident). X fetched once,
// no spill, no identity re-read.

#define IMG   2000
#define BSZ   10
#define TC    200                 // chunk size = 2000/10
#define CHW   (IMG * IMG)         // 4,000,000
#define NW4   (TC / 4)            // 50 float4 slots per chunk-row slice
#define RPITCH 12                 // padded Rt row (float4-aligned: 48 B)

__global__ __launch_bounds__(512, 4)
void reset_rowline(const float* __restrict__ x,
                   const float* __restrict__ leftm,
                   const float* __restrict__ rightm,
                   float* __restrict__ out)
{
    // Y[ih][jw][wo4] : 10*10*50 float4 = 80,000 B
    __shared__ __align__(16) float4 Ysh[BSZ * BSZ * NW4];
    // Rt[jh][ih] = rightm[ih][jh], padded to 12 floats/row
    __shared__ __align__(16) float  Rts[BSZ * RPITCH];

    const int t = threadIdx.x;
    if (t < BSZ * RPITCH) {
        const int jh = t / RPITCH, c = t - jh * RPITCH;
        Rts[t] = (c < BSZ) ? rightm[c * BSZ + jh] : 0.0f;
    }

    const int bid = blockIdx.x;        // 0..3199
    const int b   = bid / TC;          // batch index
    const int h   = bid % TC;          // intra-chunk row offset

    const int  ih     = t / NW4;       // 0..9  (valid for t < 500)
    const int  wo4    = t - ih * NW4;  // 0..49
    const bool active = (t < BSZ * NW4);

    // ---- load X row-slice: 10 float4s, each inst ~800B-contiguous per wave
    float4 x4[BSZ];
    const float4* rowp = nullptr;
    if (active) {
        rowp = (const float4*)(x + (size_t)b * CHW + (size_t)(ih * TC + h) * IMG);
        #pragma unroll
        for (int iw = 0; iw < BSZ; ++iw)
            x4[iw] = rowp[iw * NW4 + wo4];
    }

    // ---- phase A: Y[ih][jw][wo4] = sum_iw L[jw][iw] * x4[iw]
    // L indices are compile-time + uniform -> compiler emits s_load (SGPR).
    if (active) {
        #pragma unroll
        for (int jw = 0; jw < BSZ; ++jw) {
            const float l0 = leftm[jw * BSZ + 0];
            float4 y;
            y.x = l0 * x4[0].x; y.y = l0 * x4[0].y;
            y.z = l0 * x4[0].z; y.w = l0 * x4[0].w;
            #pragma unroll
            for (int iw = 1; iw < BSZ; ++iw) {
                const float l = leftm[jw * BSZ + iw];
                y.x += l * x4[iw].x; y.y += l * x4[iw].y;
                y.z += l * x4[iw].z; y.w += l * x4[iw].w;
            }
            Ysh[(ih * BSZ + jw) * NW4 + wo4] = y;
        }
    }

    __syncthreads();

    // ---- phase B: x4[jw] += sum_ih' Rt[jh][ih'] * Y[ih'][jw][wo4]
    // (jh = ih for this thread; x4 currently holds the identity term)
    if (active) {
        const int jh = ih;
        float r[BSZ];
        {
            const float4 ra = *(const float4*)&Rts[jh * RPITCH + 0];
            const float4 rb = *(const float4*)&Rts[jh * RPITCH + 4];
            const float4 rc = *(const float4*)&Rts[jh * RPITCH + 8];
            r[0] = ra.x; r[1] = ra.y; r[2] = ra.z; r[3] = ra.w;
            r[4] = rb.x; r[5] = rb.y; r[6] = rb.z; r[7] = rb.w;
            r[8] = rc.x; r[9] = rc.y;
        }
        #pragma unroll
        for (int ihp = 0; ihp < BSZ; ++ihp) {
            const float rr = r[ihp];
            #pragma unroll
            for (int jw = 0; jw < BSZ; ++jw) {
                const float4 y = Ysh[(ihp * BSZ + jw) * NW4 + wo4];
                x4[jw].x += rr * y.x; x4[jw].y += rr * y.y;
                x4[jw].z += rr * y.z; x4[jw].w += rr * y.w;
            }
        }
        // ---- store: 10 float4s, contiguous 1024B per wave-instruction
        float4* orow = (float4*)(out + (size_t)b * CHW + (size_t)(jh * TC + h) * IMG);
        #pragma unroll
        for (int jw = 0; jw < BSZ; ++jw)
            orow[jw * NW4 + wo4] = x4[jw];
    }
}

extern "C" void kernel_launch(void* const* d_in, const int* in_sizes, int n_in,
                              void* d_out, int out_size, void* d_ws, size_t ws_size,
                              hipStream_t stream) {
    const float* x = (const float*)d_in[0];
    const float* L = (const float*)d_in[1];
    const float* R = (const float*)d_in[2];
    float* out = (float*)d_out;
    // one block per (b, h): 16 * 200 = 3200 blocks, 512 threads (500 active)
    reset_rowline<<<3200, 512, 0, stream>>>(x, L, R, out);
}